// Round 11
// baseline (795.480 us; speedup 1.0000x reference)
//
#include <hip/hip_runtime.h>

#define T_TOK   8192
#define M_MORPH 12
#define NMORPH  (T_TOK * M_MORPH)   // 98304

typedef float f32x4 __attribute__((ext_vector_type(4)));
typedef float f32x2 __attribute__((ext_vector_type(2)));
typedef short s16x8 __attribute__((ext_vector_type(8)));

__device__ __forceinline__ float sigmoidf_(float x) {
    return __fdividef(1.f, 1.f + __expf(-x));
}

__device__ __forceinline__ int rowof(int s, int mode, int N) {
    if (mode == 0) return s;
    if (mode == 1) { int m = s % M_MORPH; return s + (M_MORPH - 1) - 2 * m; }
    return N - 1 - s;
}

// packed fp32 FMA: acc = w*h + acc (exact IEEE fma per lane-half, full rate)
#define PKFMA(acc, w, h) \
    asm("v_pk_fma_f32 %0, %1, %2, %0" : "+v"(acc) : "v"(w), "v"(h))

__device__ __forceinline__ void half_swap(float v, float& lo_b, float& hi_b) {
#if __has_builtin(__builtin_amdgcn_permlane32_swap)
    auto r = __builtin_amdgcn_permlane32_swap(__float_as_uint(v), __float_as_uint(v),
                                              false, false);
    lo_b = __uint_as_float((unsigned)r[0]);
    hi_b = __uint_as_float((unsigned)r[1]);
#else
    const float e = __shfl_xor(v, 32);
    const bool lo = ((threadIdx.x & 63) < 32);
    lo_b = lo ? v : e;
    hi_b = lo ? e : v;
#endif
}

// split f32 pair -> packed bf16 hi dword + lo dword (truncation split)
__device__ __forceinline__ void bf16_split_pair(float x0, float x1,
                                                unsigned& hi, unsigned& lo) {
    const unsigned u0 = __float_as_uint(x0);
    const unsigned u1 = __float_as_uint(x1);
    hi = (u0 >> 16) | (u1 & 0xFFFF0000u);
    const float h0 = __uint_as_float(u0 & 0xFFFF0000u);
    const float h1 = __uint_as_float(u1 & 0xFFFF0000u);
    lo = (__float_as_uint(x0 - h0) >> 16)
       | (__float_as_uint(x1 - h1) & 0xFFFF0000u);
}

// ---------------------------------------------------------------------------
// Pre-split LSTM input weights into frag-ready bf16 hi/lo tables.
// ---------------------------------------------------------------------------
__global__ void prep_B(const float* __restrict__ W, const float* __restrict__ b,
                       unsigned short* __restrict__ Bh, unsigned short* __restrict__ Bl,
                       float* __restrict__ bcat, int WK, int KPAD) {
    const int n = blockIdx.x;        // 0..255
    const int k = threadIdx.x;       // 0..KPAD-1
    const int dir = n >> 7, r = n & 127;
    float v = (k < WK) ? W[(size_t)(dir * 128 + r) * WK + k] : 0.f;
    unsigned int u = __float_as_uint(v);
    unsigned short hb = (unsigned short)(u >> 16);
    float fh = __uint_as_float(u & 0xFFFF0000u);
    float lo = v - fh;
    unsigned short lb = (unsigned short)(__float_as_uint(lo) >> 16);
    Bh[(size_t)n * KPAD + k] = hb;
    Bl[(size_t)n * KPAD + k] = lb;
    if (k == 0) bcat[n] = b[dir * 128 + r];
}

// ---------------------------------------------------------------------------
// X[r][256] = A[r][AS](first KACT) @ Wcat[256][K]^T + bcat via split-bf16
// MFMA. PAIRED=false: natural column order (for the MFMA-batched chain).
// PAIRED=true: round-5 paired layout for the scalar token chain.
// ---------------------------------------------------------------------------
template <int KACT, int KPAD, int AS, bool PAIRED>
__global__ __launch_bounds__(256, 2) void gemm_mfma(const float* __restrict__ A,
                                                    const unsigned short* __restrict__ Bh,
                                                    const unsigned short* __restrict__ Bl,
                                                    const float* __restrict__ bc,
                                                    float* __restrict__ X) {
    const int lane = threadIdx.x & 63;
    const int wave = threadIdx.x >> 6;
    const int col = lane & 15;
    const int kc  = (lane >> 4) * 8;
    const int row0 = blockIdx.x * 128 + wave * 32;

    f32x4 acc[2][16];
#pragma unroll
    for (int ct = 0; ct < 16; ++ct) {
        const float bv = bc[ct * 16 + col];
        f32x4 v; v[0] = bv; v[1] = bv; v[2] = bv; v[3] = bv;
        acc[0][ct] = v; acc[1][ct] = v;
    }

    const float* a0 = A + (size_t)(row0 + col) * AS;
    const float* a1 = A + (size_t)(row0 + 16 + col) * AS;

#pragma unroll
    for (int ks = 0; ks < KPAD / 32; ++ks) {
        const int kb = ks * 32 + kc;
        s16x8 ah[2], al[2];
#pragma unroll
        for (int rt = 0; rt < 2; ++rt) {
            const float* ap = (rt ? a1 : a0) + kb;
            float av[8];
#pragma unroll
            for (int h = 0; h < 2; ++h) {
                float4 t; t.x = t.y = t.z = t.w = 0.f;
                if ((ks + 1) * 32 <= KACT || kb + h * 4 < KACT)
                    t = *(const float4*)(ap + h * 4);
                av[h * 4 + 0] = t.x; av[h * 4 + 1] = t.y;
                av[h * 4 + 2] = t.z; av[h * 4 + 3] = t.w;
            }
#pragma unroll
            for (int j = 0; j < 8; ++j) {
                const unsigned int u = __float_as_uint(av[j]);
                const unsigned short hb = (unsigned short)(u >> 16);
                const float fh = __uint_as_float(u & 0xFFFF0000u);
                const float lov = av[j] - fh;
                const unsigned short lb = (unsigned short)(__float_as_uint(lov) >> 16);
                ah[rt][j] = (short)hb;
                al[rt][j] = (short)lb;
            }
        }

        const unsigned short* bhp = Bh + (size_t)col * KPAD + kb;
        const unsigned short* blp = Bl + (size_t)col * KPAD + kb;
#pragma unroll
        for (int ct = 0; ct < 16; ++ct) {
            const s16x8 bh8 = *(const s16x8*)(bhp + (size_t)ct * 16 * KPAD);
            const s16x8 bl8 = *(const s16x8*)(blp + (size_t)ct * 16 * KPAD);
#pragma unroll
            for (int rt = 0; rt < 2; ++rt) {
                acc[rt][ct] = __builtin_amdgcn_mfma_f32_16x16x32_bf16(ah[rt], bh8, acc[rt][ct], 0, 0, 0);
                acc[rt][ct] = __builtin_amdgcn_mfma_f32_16x16x32_bf16(ah[rt], bl8, acc[rt][ct], 0, 0, 0);
                acc[rt][ct] = __builtin_amdgcn_mfma_f32_16x16x32_bf16(al[rt], bh8, acc[rt][ct], 0, 0, 0);
            }
        }
    }

    const int r_in = (lane >> 4) * 4;
    if constexpr (!PAIRED) {
#pragma unroll
        for (int rt = 0; rt < 2; ++rt)
#pragma unroll
            for (int ct = 0; ct < 16; ++ct)
#pragma unroll
                for (int i = 0; i < 4; ++i)
                    X[(size_t)(row0 + rt * 16 + r_in + i) * 256 + ct * 16 + col] = acc[rt][ct][i];
    } else {
#pragma unroll
        for (int rt = 0; rt < 2; ++rt)
#pragma unroll
            for (int g = 0; g < 2; ++g)
#pragma unroll
                for (int ct2 = 0; ct2 < 4; ++ct2) {
                    const int ct = g * 8 + ct2;
                    const int c  = ct * 16 + col;
                    const int cm = c & 127;
                    const int nc = g * 128 + cm * 2;
#pragma unroll
                    for (int i = 0; i < 4; ++i) {
                        f32x2 v2;
                        v2[0] = acc[rt][ct][i];
                        v2[1] = acc[rt][ct + 4][i];
                        *(f32x2*)&X[(size_t)(row0 + rt * 16 + r_in + i) * 256 + nc] = v2;
                    }
                }
    }
}

// ---------------------------------------------------------------------------
// MFMA-BATCHED LSTM chain (morph level): 16 same-direction chunks ride as the
// 16 columns of mfma_f32_16x16x32_bf16. Per step:
//   G[128][16] = X(step rows) + Whh[128][32] @ H[32][16]   (24 split-bf16 MFMAs)
// C/D layout (col=lane&15=chunk, row=(lane>>4)*4+reg) puts gates i/f/g/o of
// h-index j = 16p+4rg+r in tiles {p,2+p,4+p,6+p} of the SAME lane ->
// activations are lane-local. h -> next B-fragment via a 2KB LDS transpose
// (pad 36 floats/chunk: 2-way bank alias = free). Chunk boundaries and Wu
// are the PROVEN baseline (Lc=96, Wu=64); chunk 0 runs at its own per-lane
// offset (ws=0 -> no leading garbage; trailing steps store to dump).
// ---------------------------------------------------------------------------
template <int DM, int SL>
__device__ __forceinline__ void mstep(
    const char* __restrict__ xb, char* __restrict__ hb,
    float* __restrict__ dl, float* __restrict__ Hls,
    const int col, const int rg,
    const s16x8 (&wh)[8], const s16x8 (&wl)[8],
    s16x8& bh, s16x8& bl,
    f32x4 (&q)[8], f32x4 (&cst)[2],
    int& su, const int cs, const int ce,
    int& pf_b, int& m_pf,
    int& st_b, int& m_st, int& tk_b)
{
    // G = X + Whh*h  (h from previous step's B-fragment; zero at t=0)
    f32x4 acc[8];
#pragma unroll
    for (int tt = 0; tt < 8; ++tt) {
        acc[tt] = __builtin_amdgcn_mfma_f32_16x16x32_bf16(wh[tt], bh, q[tt], 0, 0, 0);
        acc[tt] = __builtin_amdgcn_mfma_f32_16x16x32_bf16(wh[tt], bl, acc[tt], 0, 0, 0);
        acc[tt] = __builtin_amdgcn_mfma_f32_16x16x32_bf16(wl[tt], bh, acc[tt], 0, 0, 0);
    }

    // prefetch X rows for step t+2 into q (unconditional; rows past chunk end
    // read adjacent workspace -- never consumed)
    {
        const char* xp = xb + pf_b;
#pragma unroll
        for (int tt = 0; tt < 8; ++tt)
            q[tt] = *(const f32x4*)(xp + tt * 64);
        if (DM == 1) {
            const bool w = (m_pf == 11);
            pf_b += w ? 23 * 1024 : -1024;
            m_pf = w ? 0 : m_pf + 1;
        } else {
            pf_b += 1024;
        }
    }

    // activations: lane-local gates
    f32x4 v0, v1;
#pragma unroll
    for (int p = 0; p < 2; ++p) {
#pragma unroll
        for (int r = 0; r < 4; ++r) {
            const float gi = acc[0 + p][r], gf = acc[2 + p][r];
            const float gg = acc[4 + p][r], go = acc[6 + p][r];
            const float si = sigmoidf_(gi);
            const float sf = sigmoidf_(gf);
            const float tg = 2.f * sigmoidf_(2.f * gg) - 1.f;
            const float so = sigmoidf_(go);
            const float cn = sf * cst[p][r] + si * tg;
            cst[p][r] = cn;
            const float th = 2.f * sigmoidf_(2.f * cn) - 1.f;
            const float hv = so * th;
            if (p == 0) v0[r] = hv; else v1[r] = hv;
        }
    }

    // store h (per-lane predicate; inactive -> dump slot)
    {
        bool act = (su >= cs) && (su < ce);
        if (SL) act = act && ((DM == 1) ? (m_st == 0) : (m_st == 11));
        char* base = hb + (SL ? tk_b : st_b);
        float* a0 = act ? (float*)base : dl;
        float* a1 = act ? (float*)(base + 64) : (dl + 4);
        *(f32x4*)a0 = v0;
        *(f32x4*)a1 = v1;

        ++su;
        if (DM == 1) {
            const bool w = (m_st == 11);
            st_b += w ? 23 * 256 : -256;
            if (SL) tk_b += w ? 256 : 0;
            m_st = w ? 0 : m_st + 1;
        } else {
            st_b += 256;
            if (SL) {
                const bool w = (m_st == 11);
                tk_b += w ? 256 : 0;
                m_st = w ? 0 : m_st + 1;
            }
        }
    }

    // repack h -> B fragment via LDS transpose (wave-synchronous, no barrier)
    *(f32x4*)&Hls[col * 36 + 4 * rg]      = v0;
    *(f32x4*)&Hls[col * 36 + 16 + 4 * rg] = v1;
    const f32x4 r0 = *(const f32x4*)&Hls[col * 36 + 8 * rg];
    const f32x4 r1 = *(const f32x4*)&Hls[col * 36 + 8 * rg + 4];
    union { s16x8 s; unsigned u[4]; } BH, BL;
    bf16_split_pair(r0[0], r0[1], BH.u[0], BL.u[0]);
    bf16_split_pair(r0[2], r0[3], BH.u[1], BL.u[1]);
    bf16_split_pair(r1[0], r1[1], BH.u[2], BL.u[2]);
    bf16_split_pair(r1[2], r1[3], BH.u[3], BL.u[3]);
    bh = BH.s; bl = BL.s;
}

template <int DM, int SL>
__device__ __forceinline__ void mrun(
    const float* __restrict__ Xn, const float* __restrict__ Wd,
    float* __restrict__ Hout, float* __restrict__ dump,
    float* __restrict__ Hls,
    const int dir, const int col, const int rg, const int lane,
    const int N, const int Lc, const int Wu, const int nsteps)
{
    const int g  = blockIdx.x * 16 + col;          // global chunk id
    const int cs = g * Lc;
    const int ce = cs + Lc;
    const int off = (g == 0) ? 0 : cs - Wu;

    // Whh A-fragments (bf16 hi/lo), built once: lane holds
    // Whh[16tt+col][rg*8 + j], j=0..7
    s16x8 wh[8], wl[8];
#pragma unroll
    for (int tt = 0; tt < 8; ++tt) {
        const float* wr = Wd + (size_t)(tt * 16 + col) * 32 + rg * 8;
        const float4 w0 = *(const float4*)(wr);
        const float4 w1 = *(const float4*)(wr + 4);
        union { s16x8 s; unsigned u[4]; } H_, L_;
        bf16_split_pair(w0.x, w0.y, H_.u[0], L_.u[0]);
        bf16_split_pair(w0.z, w0.w, H_.u[1], L_.u[1]);
        bf16_split_pair(w1.x, w1.y, H_.u[2], L_.u[2]);
        bf16_split_pair(w1.z, w1.w, H_.u[3], L_.u[3]);
        wh[tt] = H_.s; wl[tt] = L_.s;
    }

    const char* xb = (const char*)Xn + dir * 512 + rg * 16;
    char* hb = (char*)Hout + (size_t)(dir * 32 + 4 * rg) * 4;
    float* dl = dump + ((size_t)(blockIdx.x * 2 + dir) * 64 + lane) * 8;

    // prologue: rows for t=0, t=1; prefetch state at t=2
    int m = off % 12;
    int rb = ((DM == 1) ? (off + 11 - 2 * m) : off) * 1024;
    f32x4 q0[8], q1[8];
    {
        const char* xp = xb + rb;
#pragma unroll
        for (int tt = 0; tt < 8; ++tt) q0[tt] = *(const f32x4*)(xp + tt * 64);
    }
    if (DM == 1) { const bool w = (m == 11); rb += w ? 23 * 1024 : -1024; m = w ? 0 : m + 1; }
    else rb += 1024;
    {
        const char* xp = xb + rb;
#pragma unroll
        for (int tt = 0; tt < 8; ++tt) q1[tt] = *(const f32x4*)(xp + tt * 64);
    }
    int m_pf = m, pf_b = rb;
    if (DM == 1) { const bool w = (m_pf == 11); pf_b += w ? 23 * 1024 : -1024; m_pf = w ? 0 : m_pf + 1; }
    else pf_b += 1024;

    int m_st = off % 12;
    int st_b = ((DM == 1) ? (off + 11 - 2 * m_st) : off) * 256;
    int tk_b = (off / 12) * 256;
    int su = off;

    f32x4 cst[2];
    cst[0][0] = 0.f; cst[0][1] = 0.f; cst[0][2] = 0.f; cst[0][3] = 0.f;
    cst[1] = cst[0];
    s16x8 bh = {0, 0, 0, 0, 0, 0, 0, 0};
    s16x8 bl = {0, 0, 0, 0, 0, 0, 0, 0};

#pragma unroll 1
    for (int t = 0; t < nsteps; t += 2) {
        mstep<DM, SL>(xb, hb, dl, Hls, col, rg, wh, wl, bh, bl, q0, cst,
                      su, cs, ce, pf_b, m_pf, st_b, m_st, tk_b);
        mstep<DM, SL>(xb, hb, dl, Hls, col, rg, wh, wl, bh, bl, q1, cst,
                      su, cs, ce, pf_b, m_pf, st_b, m_st, tk_b);
    }
}

template <int BDM, int SL>
__global__ __launch_bounds__(64)
__attribute__((amdgpu_waves_per_eu(1, 1)))
void lstm_mfma(const float* __restrict__ Xn, const float* __restrict__ Whhall,
               float* __restrict__ Hout, float* __restrict__ dump,
               int N, int Lc, int Wu, int nsteps) {
    __shared__ __align__(16) float Hls[16 * 36];
    const int lane = threadIdx.x;
    const int col = lane & 15, rg = lane >> 4;
    const int dir = blockIdx.y;
    const float* Wd = Whhall + (size_t)dir * 128 * 32;

    if (dir == 0)
        mrun<0,   SL>(Xn, Wd, Hout, dump, Hls, dir, col, rg, lane, N, Lc, Wu, nsteps);
    else
        mrun<BDM, SL>(Xn, Wd, Hout, dump, Hls, dir, col, rg, lane, N, Lc, Wu, nsteps);
}

// ---------------------------------------------------------------------------
// Scalar chunked LSTM chain (token level; proven r7 structure, paired X).
// ---------------------------------------------------------------------------
template <int DM, int SL>
__device__ __forceinline__ void chain_body(
    const float* __restrict__ Xc, float* __restrict__ HoutLane,
    const bool lo, const int lane,
    f32x2 (&wa)[16], f32x2 (&wb)[16], float* sh,
    const int N, const int cs, const int ce, const int ws)
{
    const float cg = lo ? 2.f : 1.f;
    const float ca = lo ? -1.f : 0.f;

    f32x2 q[8];
#pragma unroll
    for (int p = 0; p < 8; ++p) {
        const int rp = rowof(ws + p, DM, N);
        q[p] = *(const f32x2*)(Xc + (size_t)rp * 256);
    }

    int mp = (ws + 8) % M_MORPH;
    int pb;
    {
        const int sp0 = ws + 8;
        int rp0;
        if (DM == 1)      rp0 = sp0 + 11 - 2 * mp;
        else if (DM == 2) rp0 = N - 1 - sp0;
        else              rp0 = sp0;
        pb = rp0 * 1024;
    }

    int ms = ws % M_MORPH;
    int rs;
    if (DM == 1)      rs = ws + 11 - 2 * ms;
    else if (DM == 2) rs = N - 1 - ws;
    else              rs = ws;
    int tk = ws / M_MORPH;

    float hreg = 0.f, c = 0.f;

#pragma unroll 1
    for (int s = ws; s < ce; s += 8) {
#pragma unroll
        for (int u = 0; u < 8; ++u) {
            const int su = s + u;
            const float x1 = q[u][0], x2 = q[u][1];
            {
                const int sp = su + 8;
                const int ob = (sp < ce) ? pb : 0;
                q[u] = *(const f32x2*)((const char*)Xc + ob);
                if (DM == 1) {
                    if (mp == 11) { mp = 0; pb += 23 * 1024; }
                    else          { ++mp; pb -= 1024; }
                } else if (DM == 2) { pb -= 1024; }
                else                { pb += 1024; }
            }

            sh[lane] = hreg;
            f32x4 hq[8];
            {
                const f32x4* s4 = (const f32x4*)sh;
#pragma unroll
                for (int i = 0; i < 8; ++i) hq[i] = s4[i];
            }

            f32x2 a01 = {x1, 0.f}, a23 = {0.f, 0.f};
            f32x2 b01 = {x2, 0.f}, b23 = {0.f, 0.f};
#pragma unroll
            for (int i = 0; i < 8; ++i) {
                f32x2 hlo = __builtin_shufflevector(hq[i], hq[i], 0, 1);
                f32x2 hhi = __builtin_shufflevector(hq[i], hq[i], 2, 3);
                PKFMA(a01, wa[2 * i],     hlo);
                PKFMA(a23, wa[2 * i + 1], hhi);
                PKFMA(b01, wb[2 * i],     hlo);
                PKFMA(b23, wb[2 * i + 1], hhi);
            }
            const float g1 = (a01[0] + a01[1]) + (a23[0] + a23[1]);
            const float g2 = (b01[0] + b01[1]) + (b23[0] + b23[1]);

            const float s1 = sigmoidf_(g1);
            const float uu = sigmoidf_(cg * g2);
            const float t2 = fmaf(cg, uu, ca);

            float si, sf, tg, so;
            half_swap(s1, si, sf);
            half_swap(t2, tg, so);

            c = sf * c + si * tg;
            const float th = 2.f * sigmoidf_(2.f * c) - 1.f;
            hreg = so * th;

            if (!SL) {
                if (su >= cs) {
                    if (lo) HoutLane[(size_t)rs * 64] = hreg;
                }
            } else {
                const bool last = (DM == 1) ? (ms == 0) : (ms == 11);
                if (su >= cs && last) {
                    if (lo) HoutLane[(size_t)tk * 64] = hreg;
                }
            }

            if (DM == 1) {
                if (ms == 11) { ms = 0; ++tk; rs += 23; }
                else          { ++ms; --rs; }
            } else if (DM == 2) {
                --rs;
            } else {
                ++rs;
                if (SL) { if (ms == 11) { ms = 0; ++tk; } else ++ms; }
            }
        }
    }
}

template <int BDM, int SL>
__global__ __launch_bounds__(64)
__attribute__((amdgpu_waves_per_eu(2, 2)))
void lstm_chain_t(const float* __restrict__ Xall,
                  const float* __restrict__ Whhall,
                  float* __restrict__ Hout,
                  int N, int Lc, int Wu) {
    __shared__ __align__(16) float sh[64];
    const int lane = threadIdx.x;
    const int dir = blockIdx.y;
    const float* Whh = Whhall + dir * 128 * 32;

    const int cs = blockIdx.x * Lc;
    if (cs >= N) return;
    int ce = cs + Lc; if (ce > N) ce = N;
    int ws = cs - Wu; if (ws < 0) ws = 0;

    f32x2 wa[16], wb[16];
    {
        const f32x2* w1 = (const f32x2*)(Whh + lane * 32);
        const f32x2* w2 = (const f32x2*)(Whh + (lane + 64) * 32);
#pragma unroll
        for (int i = 0; i < 16; ++i) { wa[i] = w1[i]; wb[i] = w2[i]; }
    }
#pragma unroll
    for (int i = 0; i < 16; ++i) {
        asm volatile("" : "+v"(wa[i]));
        asm volatile("" : "+v"(wb[i]));
    }

    const float* Xc = Xall + dir * 128 + lane * 2;
    float* HoutLane = Hout + dir * 32 + lane;
    const bool lo = (lane < 32);

    if (dir == 0)
        chain_body<0,   SL>(Xc, HoutLane, lo, lane, wa, wb, sh, N, cs, ce, ws);
    else
        chain_body<BDM, SL>(Xc, HoutLane, lo, lane, wa, wb, sh, N, cs, ce, ws);
}

// ---------------------------------------------------------------------------
__global__ __launch_bounds__(256) void build_embs(const float* __restrict__ tokvec,
                                                  const float* __restrict__ dp_emb,
                                                  const int* __restrict__ dp_in,
                                                  const float* __restrict__ feat,
                                                  float* __restrict__ embs) {
    const int idx = blockIdx.x * 256 + threadIdx.x;
    if (idx >= T_TOK * 96) return;
    const int t = idx / 96, i = idx % 96;
    float v;
    if (i < 64)      v = tokvec[(size_t)t * 64 + i];
    else if (i < 68) v = dp_emb[dp_in[t] * 4 + (i - 64)];
    else if (i == 68) v = feat[t];
    else             v = 0.f;
    embs[idx] = v;
}

// ---------------------------------------------------------------------------
__global__ __launch_bounds__(256) void epilogue_k(const float* __restrict__ Ht1,
                                                  const float* __restrict__ Wout,
                                                  const float* __restrict__ bout,
                                                  const int* __restrict__ maskp,
                                                  float* __restrict__ out) {
    const int wid = threadIdx.x >> 6;
    const int lane = threadIdx.x & 63;
    const int t = blockIdx.x * 4 + wid;
    float acc = -1e30f;
    if (lane < 44) {
        acc = bout[lane];
        const float* wr = Wout + lane * 64;
        const float* hr = Ht1 + (size_t)t * 64;
#pragma unroll
        for (int k = 0; k < 64; ++k) acc += hr[k] * wr[k];
        if (lane == 43 && maskp[t] <= 0) acc = 1.0f;
        acc = fmaxf(acc, 0.f);
    }
    float mx = acc;
#pragma unroll
    for (int off = 32; off >= 1; off >>= 1) mx = fmaxf(mx, __shfl_xor(mx, off));
    const float e = (lane < 44) ? __expf(acc - mx) : 0.f;
    float ssum = e;
#pragma unroll
    for (int off = 32; off >= 1; off >>= 1) ssum += __shfl_xor(ssum, off);
    if (lane < 44) out[(size_t)t * 44 + lane] = e / ssum;
}

// ---------------------------------------------------------------------------
extern "C" void kernel_launch(void* const* d_in, const int* in_sizes, int n_in,
                              void* d_out, int out_size, void* d_ws, size_t ws_size,
                              hipStream_t stream) {
    const float* morp  = (const float*)d_in[0];
    const float* feat  = (const float*)d_in[1];
    const float* dpemb = (const float*)d_in[2];
    const float* mWih0 = (const float*)d_in[3];
    const float* mWhh0 = (const float*)d_in[4];
    const float* mb0   = (const float*)d_in[5];
    const float* mWih1 = (const float*)d_in[6];
    const float* mWhh1 = (const float*)d_in[7];
    const float* mb1   = (const float*)d_in[8];
    const float* tWih0 = (const float*)d_in[9];
    const float* tWhh0 = (const float*)d_in[10];
    const float* tb0   = (const float*)d_in[11];
    const float* tWih1 = (const float*)d_in[12];
    const float* tWhh1 = (const float*)d_in[13];
    const float* tb1   = (const float*)d_in[14];
    const float* Wout  = (const float*)d_in[15];
    const float* bout  = (const float*)d_in[16];
    const int*   dpin  = (const int*)d_in[17];
    const int*   maskp = (const int*)d_in[18];
    float* out = (float*)d_out;

    float* w = (float*)d_ws;
    size_t off = 0;
    float* X0     = w + off; off += (size_t)NMORPH * 256;
    float* Hcat0  = w + off; off += (size_t)NMORPH * 64;
    float* tokvec = w + off; off += (size_t)T_TOK * 64;
    float* embs   = w + off; off += (size_t)T_TOK * 96;
    float* Ht0    = w + off; off += (size_t)T_TOK * 64;
    float* Ht1    = w + off; off += (size_t)T_TOK * 64;
    unsigned short* Bh = (unsigned short*)(w + off); off += 256 * 128 / 2;
    unsigned short* Bl = (unsigned short*)(w + off); off += 256 * 128 / 2;
    float* bcat   = w + off; off += 256;
    float* Xt = X0;
    // dump for lstm_mfma inactive stores: reuse embs (dead during morph;
    // fully overwritten by build_embs). usage: 64 blk * 2 dir * 64 lanes * 8
    // floats = 64K floats << T_TOK*96.
    float* dump = embs;
    (void)ws_size; (void)in_sizes; (void)n_in; (void)out_size;

    // ---- morpheme-level BiLSTM: MFMA-batched chains (natural X layout) ----
    prep_B<<<256, 128, 0, stream>>>(mWih0, mb0, Bh, Bl, bcat, 100, 128);
    gemm_mfma<100, 128, 100, false><<<NMORPH / 128, 256, 0, stream>>>(morp, Bh, Bl, bcat, X0);
    lstm_mfma<1, 0><<<dim3(64, 2), 64, 0, stream>>>(X0, mWhh0, Hcat0, dump, NMORPH, 96, 64, 160);
    prep_B<<<256, 64, 0, stream>>>(mWih1, mb1, Bh, Bl, bcat, 64, 64);
    gemm_mfma<64, 64, 64, false><<<NMORPH / 128, 256, 0, stream>>>(Hcat0, Bh, Bl, bcat, X0);
    lstm_mfma<1, 1><<<dim3(64, 2), 64, 0, stream>>>(X0, mWhh1, tokvec, dump, NMORPH, 96, 64, 160);

    // ---- token-level BiLSTM: proven scalar chains (paired X layout) ----
    build_embs<<<(T_TOK * 96) / 256, 256, 0, stream>>>(tokvec, dpemb, dpin, feat, embs);
    prep_B<<<256, 96, 0, stream>>>(tWih0, tb0, Bh, Bl, bcat, 69, 96);
    gemm_mfma<96, 96, 96, true><<<T_TOK / 128, 256, 0, stream>>>(embs, Bh, Bl, bcat, Xt);
    lstm_chain_t<2, 0><<<dim3(T_TOK / 32, 2), 64, 0, stream>>>(Xt, tWhh0, Ht0, T_TOK, 32, 64);
    prep_B<<<256, 64, 0, stream>>>(tWih1, tb1, Bh, Bl, bcat, 64, 64);
    gemm_mfma<64, 64, 64, true><<<T_TOK / 128, 256, 0, stream>>>(Ht0, Bh, Bl, bcat, Xt);
    lstm_chain_t<2, 0><<<dim3(T_TOK / 32, 2), 64, 0, stream>>>(Xt, tWhh1, Ht1, T_TOK, 32, 64);

    // ---- output head ----
    epilogue_k<<<T_TOK / 4, 256, 0, stream>>>(Ht1, Wout, bout, maskp, out);
}

// Round 12
// 401.777 us; speedup vs baseline: 1.9799x; 1.9799x over previous
//
#include <hip/hip_runtime.h>

#define T_TOK   8192
#define M_MORPH 12
#define NMORPH  (T_TOK * M_MORPH)   // 98304

typedef float f32x4 __attribute__((ext_vector_type(4)));
typedef float f32x2 __attribute__((ext_vector_type(2)));
typedef short s16x8 __attribute__((ext_vector_type(8)));

__device__ __forceinline__ float sigmoidf_(float x) {
    return __fdividef(1.f, 1.f + __expf(-x));
}

__device__ __forceinline__ int rowof(int s, int mode, int N) {
    if (mode == 0) return s;
    if (mode == 1) { int m = s % M_MORPH; return s + (M_MORPH - 1) - 2 * m; }
    return N - 1 - s;
}

// packed fp32 FMA: acc = w*h + acc (exact IEEE fma per lane-half, full rate)
#define PKFMA(acc, w, h) \
    asm("v_pk_fma_f32 %0, %1, %2, %0" : "+v"(acc) : "v"(w), "v"(h))

// lane-half swap broadcast (1 instr, no LDS): lo_b = lanes0..31 value in both
// halves; hi_b = lanes32..63 value in both halves.
__device__ __forceinline__ void half_swap(float v, float& lo_b, float& hi_b) {
#if __has_builtin(__builtin_amdgcn_permlane32_swap)
    auto r = __builtin_amdgcn_permlane32_swap(__float_as_uint(v), __float_as_uint(v),
                                              false, false);
    lo_b = __uint_as_float((unsigned)r[0]);
    hi_b = __uint_as_float((unsigned)r[1]);
#else
    const float e = __shfl_xor(v, 32);
    const bool lo = ((threadIdx.x & 63) < 32);
    lo_b = lo ? v : e;
    hi_b = lo ? e : v;
#endif
}

// ---------------------------------------------------------------------------
// Pre-split LSTM input weights into frag-ready bf16 hi/lo tables.
// ---------------------------------------------------------------------------
__global__ void prep_B(const float* __restrict__ W, const float* __restrict__ b,
                       unsigned short* __restrict__ Bh, unsigned short* __restrict__ Bl,
                       float* __restrict__ bcat, int WK, int KPAD) {
    const int n = blockIdx.x;        // 0..255
    const int k = threadIdx.x;       // 0..KPAD-1
    const int dir = n >> 7, r = n & 127;
    float v = (k < WK) ? W[(size_t)(dir * 128 + r) * WK + k] : 0.f;
    unsigned int u = __float_as_uint(v);
    unsigned short hb = (unsigned short)(u >> 16);
    float fh = __uint_as_float(u & 0xFFFF0000u);
    float lo = v - fh;
    unsigned short lb = (unsigned short)(__float_as_uint(lo) >> 16);
    Bh[(size_t)n * KPAD + k] = hb;
    Bl[(size_t)n * KPAD + k] = lb;
    if (k == 0) bcat[n] = b[dir * 128 + r];
}

// ---------------------------------------------------------------------------
// X[r][256] = A[r][AS](first KACT) @ Wcat[256][K]^T + bcat via split-bf16
// MFMA (hi*hi + hi*lo + lo*hi).
//
// PAIRED OUTPUT LAYOUT (round-5): column c is stored at
//   d*128 + (c%64)*2 + ((c%128)/64),  d = c/128
// so the chain's lane l reads its two gate pre-activations as ONE dwordx2.
// ---------------------------------------------------------------------------
template <int KACT, int KPAD, int AS>
__global__ __launch_bounds__(256, 2) void gemm_mfma(const float* __restrict__ A,
                                                    const unsigned short* __restrict__ Bh,
                                                    const unsigned short* __restrict__ Bl,
                                                    const float* __restrict__ bc,
                                                    float* __restrict__ X) {
    const int lane = threadIdx.x & 63;
    const int wave = threadIdx.x >> 6;
    const int col = lane & 15;
    const int kc  = (lane >> 4) * 8;
    const int row0 = blockIdx.x * 128 + wave * 32;

    f32x4 acc[2][16];
#pragma unroll
    for (int ct = 0; ct < 16; ++ct) {
        const float bv = bc[ct * 16 + col];
        f32x4 v; v[0] = bv; v[1] = bv; v[2] = bv; v[3] = bv;
        acc[0][ct] = v; acc[1][ct] = v;
    }

    const float* a0 = A + (size_t)(row0 + col) * AS;
    const float* a1 = A + (size_t)(row0 + 16 + col) * AS;

#pragma unroll
    for (int ks = 0; ks < KPAD / 32; ++ks) {
        const int kb = ks * 32 + kc;
        s16x8 ah[2], al[2];
#pragma unroll
        for (int rt = 0; rt < 2; ++rt) {
            const float* ap = (rt ? a1 : a0) + kb;
            float av[8];
#pragma unroll
            for (int h = 0; h < 2; ++h) {
                float4 t; t.x = t.y = t.z = t.w = 0.f;
                if ((ks + 1) * 32 <= KACT || kb + h * 4 < KACT)
                    t = *(const float4*)(ap + h * 4);
                av[h * 4 + 0] = t.x; av[h * 4 + 1] = t.y;
                av[h * 4 + 2] = t.z; av[h * 4 + 3] = t.w;
            }
#pragma unroll
            for (int j = 0; j < 8; ++j) {
                const unsigned int u = __float_as_uint(av[j]);
                const unsigned short hb = (unsigned short)(u >> 16);
                const float fh = __uint_as_float(u & 0xFFFF0000u);
                const float lov = av[j] - fh;
                const unsigned short lb = (unsigned short)(__float_as_uint(lov) >> 16);
                ah[rt][j] = (short)hb;
                al[rt][j] = (short)lb;
            }
        }

        const unsigned short* bhp = Bh + (size_t)col * KPAD + kb;
        const unsigned short* blp = Bl + (size_t)col * KPAD + kb;
#pragma unroll
        for (int ct = 0; ct < 16; ++ct) {
            const s16x8 bh8 = *(const s16x8*)(bhp + (size_t)ct * 16 * KPAD);
            const s16x8 bl8 = *(const s16x8*)(blp + (size_t)ct * 16 * KPAD);
#pragma unroll
            for (int rt = 0; rt < 2; ++rt) {
                acc[rt][ct] = __builtin_amdgcn_mfma_f32_16x16x32_bf16(ah[rt], bh8, acc[rt][ct], 0, 0, 0);
                acc[rt][ct] = __builtin_amdgcn_mfma_f32_16x16x32_bf16(ah[rt], bl8, acc[rt][ct], 0, 0, 0);
                acc[rt][ct] = __builtin_amdgcn_mfma_f32_16x16x32_bf16(al[rt], bh8, acc[rt][ct], 0, 0, 0);
            }
        }
    }

    const int r_in = (lane >> 4) * 4;
#pragma unroll
    for (int rt = 0; rt < 2; ++rt)
#pragma unroll
        for (int ct = 0; ct < 16; ++ct) {
            const int c = ct * 16 + col;           // original column
            const int d = c >> 7;
            const int cm = c & 127;
            const int nc = d * 128 + (cm & 63) * 2 + (cm >> 6);  // paired
#pragma unroll
            for (int i = 0; i < 4; ++i)
                X[(size_t)(row0 + rt * 16 + r_in + i) * 256 + nc] = acc[rt][ct][i];
        }
}

// ---------------------------------------------------------------------------
// LSTM chain step-body, specialized on DM (0=fwd, 1=morph-bwd, 2=plain-bwd)
// and SL (store-last-morpheme). FINAL STRUCTURE — measured best (400.7 us
// total, r7): 2 waves/SIMD morph (Lc=96/Wu=64), 0.5 waves/SIMD token
// (Lc=32/Wu=64); depth-8 unconditional prefetch; incremental scalar
// row/phase state (constant deltas, morph wrap = +23 rows); 1 ds_write +
// 8 ds_read_b128 h-broadcast feeding v_pk_fma via subregister pairs;
// per-lane hoisted activation constants; conditional wave-uniform stores.
//
// Ledger of falsified alternatives (rounds 1-10): per-step vmcnt waits (r1/
// r2 ~neutral), DS-op count (r3 vs r4 equal), VMEM-op halving (r5 +8% only),
// dual-chunk ILP (r6 regression), anti-phase stagger (r8 neutral — stalls
// are independent Bernoulli, 0.66^2 = observed 44% all-stall), MFMA-batched
// 16-chunk recurrence (r10: 2.7x regression — 1/8 occupancy starves the
// serial mfma->LDS-transpose->repack chain; 164K bank conflicts).
// Wall model: wall(n waves/SIMD) ~ 900 + 350n cy/step -> n=2, Lc=96 optimal.
// Chunk geometry is numerics-critical (r0: new boundaries with Wu=64 blow
// the warm-up-error tail).
// ---------------------------------------------------------------------------
template <int DM, int SL>
__device__ __forceinline__ void chain_body(
    const float* __restrict__ Xc, float* __restrict__ HoutLane,
    const bool lo, const int lane,
    f32x2 (&wa)[16], f32x2 (&wb)[16], float* sh,
    const int N, const int cs, const int ce, const int ws)
{
    // per-lane activation constants: lo: sig(2g)*2-1 ; hi: sig(g)
    const float cg = lo ? 2.f : 1.f;
    const float ca = lo ? -1.f : 0.f;

    f32x2 q[8];
#pragma unroll
    for (int p = 0; p < 8; ++p) {
        const int rp = rowof(ws + p, DM, N);
        q[p] = *(const f32x2*)(Xc + (size_t)rp * 256);
    }

    // prefetch state for sp = ws+8
    int mp = (ws + 8) % M_MORPH;             // used only when DM==1
    int pb;                                  // prefetch row byte offset
    {
        const int sp0 = ws + 8;
        int rp0;
        if (DM == 1)      rp0 = sp0 + 11 - 2 * mp;
        else if (DM == 2) rp0 = N - 1 - sp0;
        else              rp0 = sp0;
        pb = rp0 * 1024;
    }

    // store state
    int ms = ws % M_MORPH;                   // morph phase (DM==1 or SL)
    int rs;                                  // store row (non-SL)
    if (DM == 1)      rs = ws + 11 - 2 * ms;
    else if (DM == 2) rs = N - 1 - ws;
    else              rs = ws;
    int tk = ws / M_MORPH;                   // SL only

    float hreg = 0.f, c = 0.f;

#pragma unroll 1
    for (int s = ws; s < ce; s += 8) {
#pragma unroll
        for (int u = 0; u < 8; ++u) {
            const int su = s + u;
            const float x1 = q[u][0], x2 = q[u][1];

            // unconditional prefetch; offset clamped to row 0 past chunk end
            {
                const int sp = su + 8;
                const int ob = (sp < ce) ? pb : 0;
                q[u] = *(const f32x2*)((const char*)Xc + ob);
                if (DM == 1) {
                    if (mp == 11) { mp = 0; pb += 23 * 1024; }
                    else          { ++mp; pb -= 1024; }
                } else if (DM == 2) { pb -= 1024; }
                else                { pb += 1024; }
            }

            // h broadcast via LDS: 1 write + 8 b128 reads (sub-pairs feed
            // PKFMA directly via shufflevector = subregister, no movs)
            sh[lane] = hreg;
            f32x4 hq[8];
            {
                const f32x4* s4 = (const f32x4*)sh;
#pragma unroll
                for (int i = 0; i < 8; ++i) hq[i] = s4[i];
            }

            f32x2 a01 = {x1, 0.f}, a23 = {0.f, 0.f};
            f32x2 b01 = {x2, 0.f}, b23 = {0.f, 0.f};
#pragma unroll
            for (int i = 0; i < 8; ++i) {
                f32x2 hlo = __builtin_shufflevector(hq[i], hq[i], 0, 1);
                f32x2 hhi = __builtin_shufflevector(hq[i], hq[i], 2, 3);
                PKFMA(a01, wa[2 * i],     hlo);
                PKFMA(a23, wa[2 * i + 1], hhi);
                PKFMA(b01, wb[2 * i],     hlo);
                PKFMA(b23, wb[2 * i + 1], hhi);
            }
            const float g1 = (a01[0] + a01[1]) + (a23[0] + a23[1]);  // i|f
            const float g2 = (b01[0] + b01[1]) + (b23[0] + b23[1]);  // g|o

            const float s1 = sigmoidf_(g1);
            const float uu = sigmoidf_(cg * g2);
            const float t2 = fmaf(cg, uu, ca);        // tanh(g) | sig(o)

            float si, sf, tg, so;
            half_swap(s1, si, sf);
            half_swap(t2, tg, so);

            c = sf * c + si * tg;
            const float th = 2.f * sigmoidf_(2.f * c) - 1.f;
            hreg = so * th;

            // conditional store (wave-uniform predicates)
            if (!SL) {
                if (su >= cs) {
                    if (lo) HoutLane[(size_t)rs * 64] = hreg;
                }
            } else {
                const bool last = (DM == 1) ? (ms == 0) : (ms == 11);
                if (su >= cs && last) {
                    if (lo) HoutLane[(size_t)tk * 64] = hreg;
                }
            }

            // advance store state (constant deltas)
            if (DM == 1) {
                if (ms == 11) { ms = 0; ++tk; rs += 23; }
                else          { ++ms; --rs; }
            } else if (DM == 2) {
                --rs;
            } else {
                ++rs;
                if (SL) { if (ms == 11) { ms = 0; ++tk; } else ++ms; }
            }
        }
    }
}

// BDM: the dm used for dir==1 (dir==0 is always DM=0 forward).
template <int BDM, int SL>
__global__ __launch_bounds__(64)
__attribute__((amdgpu_waves_per_eu(2, 2)))
void lstm_chain_t(const float* __restrict__ Xall,
                  const float* __restrict__ Whhall,
                  float* __restrict__ Hout,
                  int N, int Lc, int Wu) {
    __shared__ __align__(16) float sh[64];
    const int lane = threadIdx.x;
    const int dir = blockIdx.y;
    const float* Whh = Whhall + dir * 128 * 32;

    const int cs = blockIdx.x * Lc;
    if (cs >= N) return;
    int ce = cs + Lc; if (ce > N) ce = N;
    int ws = cs - Wu; if (ws < 0) ws = 0;

    // weights as f32x2 pairs (rows lane / lane+64), pinned in registers
    f32x2 wa[16], wb[16];
    {
        const f32x2* w1 = (const f32x2*)(Whh + lane * 32);
        const f32x2* w2 = (const f32x2*)(Whh + (lane + 64) * 32);
#pragma unroll
        for (int i = 0; i < 16; ++i) { wa[i] = w1[i]; wb[i] = w2[i]; }
    }
#pragma unroll
    for (int i = 0; i < 16; ++i) {
        asm volatile("" : "+v"(wa[i]));
        asm volatile("" : "+v"(wb[i]));
    }

    const float* Xc = Xall + dir * 128 + lane * 2;  // paired layout
    float* HoutLane = Hout + dir * 32 + lane;
    const bool lo = (lane < 32);

    if (dir == 0)
        chain_body<0,   SL>(Xc, HoutLane, lo, lane, wa, wb, sh, N, cs, ce, ws);
    else
        chain_body<BDM, SL>(Xc, HoutLane, lo, lane, wa, wb, sh, N, cs, ce, ws);
}

// ---------------------------------------------------------------------------
// input_embs[t] = [tok_vec(64) | dp_emb[dp_in[t]](4) | feat[t](1) | 0 pad],
// stride 96.
// ---------------------------------------------------------------------------
__global__ __launch_bounds__(256) void build_embs(const float* __restrict__ tokvec,
                                                  const float* __restrict__ dp_emb,
                                                  const int* __restrict__ dp_in,
                                                  const float* __restrict__ feat,
                                                  float* __restrict__ embs) {
    const int idx = blockIdx.x * 256 + threadIdx.x;
    if (idx >= T_TOK * 96) return;
    const int t = idx / 96, i = idx % 96;
    float v;
    if (i < 64)      v = tokvec[(size_t)t * 64 + i];
    else if (i < 68) v = dp_emb[dp_in[t] * 4 + (i - 64)];
    else if (i == 68) v = feat[t];
    else             v = 0.f;
    embs[idx] = v;
}

// ---------------------------------------------------------------------------
__global__ __launch_bounds__(64) void epilogue_k(const float* __restrict__ Ht1,
                                                 const float* __restrict__ Wout,
                                                 const float* __restrict__ bout,
                                                 const int* __restrict__ maskp,
                                                 float* __restrict__ out) {
    const int t = blockIdx.x;
    const int lane = threadIdx.x;
    float acc = -1e30f;
    if (lane < 44) {
        acc = bout[lane];
        const float* wr = Wout + lane * 64;
        const float* hr = Ht1 + (size_t)t * 64;
#pragma unroll
        for (int k = 0; k < 64; ++k) acc += hr[k] * wr[k];
        if (lane == 43 && maskp[t] <= 0) acc = 1.0f;
        acc = fmaxf(acc, 0.f);
    }
    float mx = acc;
#pragma unroll
    for (int off = 32; off >= 1; off >>= 1) mx = fmaxf(mx, __shfl_xor(mx, off));
    const float e = (lane < 44) ? __expf(acc - mx) : 0.f;
    float ssum = e;
#pragma unroll
    for (int off = 32; off >= 1; off >>= 1) ssum += __shfl_xor(ssum, off);
    if (lane < 44) out[(size_t)t * 44 + lane] = e / ssum;
}

// ---------------------------------------------------------------------------
extern "C" void kernel_launch(void* const* d_in, const int* in_sizes, int n_in,
                              void* d_out, int out_size, void* d_ws, size_t ws_size,
                              hipStream_t stream) {
    const float* morp  = (const float*)d_in[0];
    const float* feat  = (const float*)d_in[1];
    const float* dpemb = (const float*)d_in[2];
    const float* mWih0 = (const float*)d_in[3];
    const float* mWhh0 = (const float*)d_in[4];
    const float* mb0   = (const float*)d_in[5];
    const float* mWih1 = (const float*)d_in[6];
    const float* mWhh1 = (const float*)d_in[7];
    const float* mb1   = (const float*)d_in[8];
    const float* tWih0 = (const float*)d_in[9];
    const float* tWhh0 = (const float*)d_in[10];
    const float* tb0   = (const float*)d_in[11];
    const float* tWih1 = (const float*)d_in[12];
    const float* tWhh1 = (const float*)d_in[13];
    const float* tb1   = (const float*)d_in[14];
    const float* Wout  = (const float*)d_in[15];
    const float* bout  = (const float*)d_in[16];
    const int*   dpin  = (const int*)d_in[17];
    const int*   maskp = (const int*)d_in[18];
    float* out = (float*)d_out;

    float* w = (float*)d_ws;
    size_t off = 0;
    float* X0     = w + off; off += (size_t)NMORPH * 256;   // paired-layout X
    float* Hcat0  = w + off; off += (size_t)NMORPH * 64;
    float* tokvec = w + off; off += (size_t)T_TOK * 64;
    float* embs   = w + off; off += (size_t)T_TOK * 96;
    float* Ht0    = w + off; off += (size_t)T_TOK * 64;
    float* Ht1    = w + off; off += (size_t)T_TOK * 64;
    unsigned short* Bh = (unsigned short*)(w + off); off += 256 * 128 / 2;
    unsigned short* Bl = (unsigned short*)(w + off); off += 256 * 128 / 2;
    float* bcat   = w + off; off += 256;
    float* Xt = X0;
    (void)ws_size; (void)in_sizes; (void)n_in; (void)out_size;

    // ---- morpheme-level BiLSTM (chains of length 98304) ----
    prep_B<<<256, 128, 0, stream>>>(mWih0, mb0, Bh, Bl, bcat, 100, 128);
    gemm_mfma<100, 128, 100><<<NMORPH / 128, 256, 0, stream>>>(morp, Bh, Bl, bcat, X0);
    lstm_chain_t<1, 0><<<dim3(NMORPH / 96, 2), 64, 0, stream>>>(X0, mWhh0, Hcat0, NMORPH, 96, 64);
    prep_B<<<256, 64, 0, stream>>>(mWih1, mb1, Bh, Bl, bcat, 64, 64);
    gemm_mfma<64, 64, 64><<<NMORPH / 128, 256, 0, stream>>>(Hcat0, Bh, Bl, bcat, X0);
    lstm_chain_t<1, 1><<<dim3(NMORPH / 96, 2), 64, 0, stream>>>(X0, mWhh1, tokvec, NMORPH, 96, 64);

    // ---- token-level BiLSTM (chains of length 8192) ----
    build_embs<<<(T_TOK * 96) / 256, 256, 0, stream>>>(tokvec, dpemb, dpin, feat, embs);
    prep_B<<<256, 96, 0, stream>>>(tWih0, tb0, Bh, Bl, bcat, 69, 96);
    gemm_mfma<96, 96, 96><<<T_TOK / 128, 256, 0, stream>>>(embs, Bh, Bl, bcat, Xt);
    lstm_chain_t<2, 0><<<dim3(T_TOK / 32, 2), 64, 0, stream>>>(Xt, tWhh0, Ht0, T_TOK, 32, 64);
    prep_B<<<256, 64, 0, stream>>>(tWih1, tb1, Bh, Bl, bcat, 64, 64);
    gemm_mfma<64, 64, 64><<<T_TOK / 128, 256, 0, stream>>>(Ht0, Bh, Bl, bcat, Xt);
    lstm_chain_t<2, 0><<<dim3(T_TOK / 32, 2), 64, 0, stream>>>(Xt, tWhh1, Ht1, T_TOK, 32, 64);

    // ---- output head ----
    epilogue_k<<<T_TOK, 64, 0, stream>>>(Ht1, Wout, bout, maskp, out);
}